// Round 5
// baseline (359.894 us; speedup 1.0000x reference)
//
#include <hip/hip_runtime.h>
#include <math.h>

#define NH 16
#define NB 64
#define DK 64
#define NE 32768
#define NHB (NH * NB)   // 1024 compute blocks
#define TPB 256

typedef float vf4 __attribute__((ext_vector_type(4)));

// ws layout: [0..127] int bounds[NB+1] (padded), then float ksc[NH*NE]
__global__ void seg_bounds_kernel(const int* __restrict__ batch, int* __restrict__ bounds) {
    int e = blockIdx.x * 256 + threadIdx.x;
    if (e >= NE) return;
    int be = batch[e];
    if (e == 0) {
        for (int b = 0; b <= be; ++b) bounds[b] = 0;
    } else {
        int bp = batch[e - 1];
        for (int b = bp + 1; b <= be; ++b) bounds[b] = e;
    }
    if (e == NE - 1) {
        for (int b = be + 1; b <= NB; ++b) bounds[b] = NE;
    }
}

// 2048 blocks x 256 threads = 8 blocks/CU, full 32-wave residency.
// Even bid -> compute block for (h,b); odd bid -> zero-specialist for one attn row.
// Compute-block wave layout: esub = lane>>4 (edge within 4-edge group),
// dsub = (lane&15)*4 (float4 d-slice). One float4/lane = 4 rows = 1 KB
// contiguous per wave instruction for both K and V streams.
__global__ __launch_bounds__(TPB, 8) void sdpa_fused(
    const float* __restrict__ Q,      // [NH, NB, DK]
    const float* __restrict__ K,      // [NH, NE, DK]
    const float* __restrict__ V,      // [NH, NE, DK]
    const int*   __restrict__ bounds, // [NB+1]
    float* __restrict__ out,          // [NH, NB, DK]
    float* __restrict__ attn,         // [NH, NB, NE]
    float* __restrict__ ksc_base)     // [NH, NE]
{
    const int bid = blockIdx.x;
    const int tid = threadIdx.x;

    if (bid & 1) {
        // ---- zero-specialist: one attn row, skipping [start,end) ----
        const int row   = bid >> 1;             // 0..1023 == h*NB + b
        const int b     = row & (NB - 1);
        const int start = bounds[b];
        const int end   = bounds[b + 1];
        float* arow = attn + (size_t)row * NE;
        vf4 z4 = {0.f, 0.f, 0.f, 0.f};
        vf4* a4 = (vf4*)arow;
        const int c1 = start >> 2;              // full chunks before segment
        for (int i = tid; i < c1; i += TPB)
            __builtin_nontemporal_store(z4, a4 + i);
        for (int i = ((end + 3) >> 2) + tid; i < NE / 4; i += TPB)
            __builtin_nontemporal_store(z4, a4 + i);
        // ragged floats at chunk boundaries (disjoint from compute p-writes)
        if (tid < (start & 3))
            __builtin_nontemporal_store(0.f, arow + (start & ~3) + tid);
        if (tid < ((4 - (end & 3)) & 3))
            __builtin_nontemporal_store(0.f, arow + end + tid);
        return;
    }

    // ---- compute block for (h, b) ----
    const int row  = bid >> 1;
    const int h    = row >> 6;
    const int b    = row & (NB - 1);
    const int wave = tid >> 6;
    const int lane = tid & 63;
    const int esub = lane >> 4;          // which of the 4 edges this lane serves
    const int dsub = (lane & 15) << 2;   // this lane's float4 d-slice

    const int start = bounds[b];
    const int end   = bounds[b + 1];

    const float* Kh  = K + (size_t)h * NE * DK;
    const float* Vh  = V + (size_t)h * NE * DK;
    float* ksc  = ksc_base + (size_t)h * NE;
    float* arow = attn + ((size_t)h * NB + b) * NE;

    const vf4 q4 = *(const vf4*)(Q + ((size_t)h * NB + b) * DK + dsub);

    // contiguous chunk of the segment per wave
    const int S   = end - start;
    const int per = (S + 3) >> 2;
    const int cb  = start + wave * per;
    const int ce  = (cb + per < end) ? cb + per : end;

    __shared__ float sm[4], sl[4];
    __shared__ vf4 red[4][16];

    // --- P1: scores (4 edges per wave-iteration, 1 KB coalesced) + online (m,l) ---
    float m = -INFINITY, l = 0.f;
    for (int e0 = cb; e0 < ce; e0 += 4) {
        const int  eg  = e0 + esub;
        const bool act = (eg < ce);
        const int  ec  = act ? eg : (ce - 1);
        vf4 kv = *(const vf4*)(Kh + (size_t)ec * DK + dsub);
        float s = fmaf(kv.x, q4.x, fmaf(kv.y, q4.y, fmaf(kv.z, q4.z, kv.w * q4.w)));
        s += __shfl_xor(s, 1);
        s += __shfl_xor(s, 2);
        s += __shfl_xor(s, 4);
        s += __shfl_xor(s, 8);   // all 16 lanes of this edge now hold the full dot
        if (act) {
            if ((lane & 15) == 0) ksc[eg] = s;   // 4 lanes, 16 consecutive bytes
            float nm = fmaxf(m, s);
            l = l * __expf(m - nm) + __expf(s - nm);
            m = nm;
        }
    }
    // merge (m,l) across the 4 esub groups (lanes within a group are identical)
    #pragma unroll
    for (int off = 16; off <= 32; off <<= 1) {
        float om = __shfl_xor(m, off);
        float ol = __shfl_xor(l, off);
        float nm = fmaxf(m, om);
        float t1 = (l  > 0.f) ? l  * __expf(m  - nm) : 0.f;
        float t2 = (ol > 0.f) ? ol * __expf(om - nm) : 0.f;
        m = nm; l = t1 + t2;
    }
    if (lane == 0) { sm[wave] = m; sl[wave] = l; }
    __syncthreads();   // also publishes ksc stores to the block (vmcnt drain)

    float M = fmaxf(fmaxf(sm[0], sm[1]), fmaxf(sm[2], sm[3]));
    float L = 0.f;
    #pragma unroll
    for (int w = 0; w < 4; ++w)
        L += (sl[w] > 0.f) ? sl[w] * __expf(sm[w] - M) : 0.f;
    const float inv = (L > 0.f) ? 1.f / L : 0.f;

    // --- P2: normalized p into segment region (coalesced, NT) ---
    for (int e = start + tid; e < end; e += TPB)
        __builtin_nontemporal_store(__expf(ksc[e] - M) * inv, arow + e);

    // --- P3: out[d] = sum_e p_e * V[e][d], same 1 KB-coalesced layout ---
    vf4 acc = {0.f, 0.f, 0.f, 0.f};
    for (int e0 = cb; e0 < ce; e0 += 4) {
        const int  eg  = e0 + esub;
        const bool act = (eg < ce);
        const int  ec  = act ? eg : (ce - 1);
        float sv = ksc[ec];                       // 4 distinct addrs/wave, broadcast
        float p  = act ? (__expf(sv - M) * inv) : 0.f;
        vf4 vv = *(const vf4*)(Vh + (size_t)ec * DK + dsub);
        acc.x = fmaf(p, vv.x, acc.x);
        acc.y = fmaf(p, vv.y, acc.y);
        acc.z = fmaf(p, vv.z, acc.z);
        acc.w = fmaf(p, vv.w, acc.w);
    }
    #pragma unroll
    for (int off = 16; off <= 32; off <<= 1) {
        acc.x += __shfl_xor(acc.x, off);
        acc.y += __shfl_xor(acc.y, off);
        acc.z += __shfl_xor(acc.z, off);
        acc.w += __shfl_xor(acc.w, off);
    }
    if (lane < 16) red[wave][lane] = acc;
    __syncthreads();
    if (wave == 0 && lane < 16) {
        vf4 r = red[0][lane];
        vf4 r1 = red[1][lane], r2 = red[2][lane], r3 = red[3][lane];
        r.x += r1.x + r2.x + r3.x;
        r.y += r1.y + r2.y + r3.y;
        r.z += r1.z + r2.z + r3.z;
        r.w += r1.w + r2.w + r3.w;
        *(vf4*)(out + ((size_t)h * NB + b) * DK + (lane << 2)) = r;
    }
}

extern "C" void kernel_launch(void* const* d_in, const int* in_sizes, int n_in,
                              void* d_out, int out_size, void* d_ws, size_t ws_size,
                              hipStream_t stream) {
    const float* Q     = (const float*)d_in[0];
    const float* K     = (const float*)d_in[1];
    const float* V     = (const float*)d_in[2];
    const int*   batch = (const int*)d_in[3];

    float* out  = (float*)d_out;                    // [NH,NB,DK]
    float* attn = out + (size_t)NH * NB * DK;       // [NH,NB,NE]

    int*   bounds = (int*)d_ws;                     // [NB+1], padded to 512 B
    float* ksc    = (float*)d_ws + 128;             // [NH,NE]

    seg_bounds_kernel<<<NE / 256, 256, 0, stream>>>(batch, bounds);

    sdpa_fused<<<2 * NHB, TPB, 0, stream>>>(Q, K, V, bounds, out, attn, ksc);
}